// Round 6
// baseline (141.886 us; speedup 1.0000x reference)
//
#include <hip/hip_runtime.h>
#include <utility>

#define NW 14
#define NL 3
#define DIM 16384            // 2^14
#define NGATES (NL * NW)     // 42 fused RY*RX gates
#define TPB 1024
#define NPH (NL * 4)         // phases: per layer 4+4+4+2 gates

typedef float v2f __attribute__((ext_vector_type(2)));

struct Phase {
    unsigned short sx[16]  = {};  // subset XORs of the phase's masks
    unsigned char  pos[12] = {};  // non-pivot bit positions (ascending)
    unsigned short vm[4]   = {};  // value-parity masks per gate
    unsigned char  cpar[4] = {};  // per-gate per-pair compile-time role bits
    unsigned char  gbase   = 0;   // first gate id
    unsigned char  K       = 0;   // gates in this phase
};
struct Sched {
    Phase          ph[NPH] = {};
    unsigned short zm[NW]  = {};  // final parity masks for <Z_w>
};

// ---- LDS swizzle sigma(i) = i ^ f(i), f linear over GF(2) from index bits 4..9
// into bank bits 0..3: g(4)=3 g(5)=2 g(6)=5 g(7)=10 g(8)=1 g(9)=2.
__host__ __device__ constexpr unsigned foldf(unsigned i) {
    unsigned u = i >> 4;   // u0=i4 u1=i5 u2=i6 u3=i7 u4=i8 u5=i9
    return ((u ^ (u >> 2) ^ (u >> 4)) & 1u)                     // bit0 = i4^i6^i8
         | (((u ^ (u >> 1) ^ (u >> 3) ^ (u >> 5)) & 1u) << 1)   // bit1 = i4^i5^i7^i9
         | (u & 12u);                                           // bit2 = i6, bit3 = i7
}
__host__ __device__ constexpr unsigned sigma(unsigned i) { return i ^ foldf(i); }

// ---------------- compile-time GF(2) schedule ----------------
constexpr Sched build_sched() {
    Sched sc{};
    unsigned A[NW] = {};
    for (int w = 0; w < NW; ++w) A[w] = 1u << (NW - 1 - w);  // wire w <-> bit 13-w
    int pidx = 0;
    for (int l = 0; l < NL; ++l) {
        unsigned rows[NW] = {};
        for (int u = 0; u < NW; ++u) rows[u] = A[u] | (1u << (NW + u));
        for (int col = 0; col < NW; ++col) {
            int piv = col;
            while (piv < NW && !((rows[piv] >> col) & 1u)) ++piv;
            if (piv >= NW) continue;
            unsigned tmp = rows[col]; rows[col] = rows[piv]; rows[piv] = tmp;
            for (int r = 0; r < NW; ++r)
                if (r != col && ((rows[r] >> col) & 1u)) rows[r] ^= rows[col];
        }
        unsigned m[NW] = {};
        for (int w = 0; w < NW; ++w) {
            unsigned mk = 0;
            for (int r = 0; r < NW; ++r) mk |= ((rows[r] >> (NW + w)) & 1u) << r;
            m[w] = mk;  // pair mask of gate (l, w)
        }
        for (int g0 = 0; g0 < NW; g0 += 4) {
            int K = (NW - g0 >= 4) ? 4 : (NW - g0);
            Phase& P = sc.ph[pidx++];
            unsigned mm[4] = { 0, 0, 0, 0 };
            for (int q = 0; q < K; ++q) mm[q] = m[g0 + q];
            for (int s = 0; s < (1 << K); ++s) {
                unsigned v = 0;
                for (int q = 0; q < K; ++q) if ((s >> q) & 1) v ^= mm[q];
                P.sx[s] = (unsigned short)v;
            }
            // Gaussian elimination preferring HIGH pivot bits
            unsigned pivmask = 0, redv[4] = {}; int pivpos[4] = {};
            for (int q = 0; q < K; ++q) {
                unsigned r = mm[q];
                for (int j = 0; j < q; ++j)
                    if ((r >> pivpos[j]) & 1u) r ^= redv[j];
                int hb = 31 - __builtin_clz(r);
                pivpos[q] = hb; redv[q] = r; pivmask |= 1u << hb;
            }
            int n = 0;
            for (int b = 0; b < NW; ++b)
                if (!((pivmask >> b) & 1u)) P.pos[n++] = (unsigned char)b;
            for (int q = 0; q < K; ++q) {
                P.vm[q] = (unsigned short)A[g0 + q];
                unsigned lowm = (1u << q) - 1u, cp = 0;
                for (int p = 0; p < (1 << K) / 2; ++p) {
                    unsigned s0 = ((p & ~lowm) << 1) | (p & lowm);
                    if (__builtin_popcount(P.sx[s0] & A[g0 + q]) & 1) cp |= 1u << p;
                }
                P.cpar[q] = (unsigned char)cp;
            }
            P.gbase = (unsigned char)(l * NW + g0);
            P.K = (unsigned char)K;
        }
        for (int w = 0; w < NW - 1; ++w) A[w + 1] ^= A[w];  // virtual CNOT chain
        A[0] ^= A[NW - 1];
    }
    for (int w = 0; w < NW; ++w) sc.zm[w] = (unsigned short)A[w];
    return sc;
}
constexpr Sched SC = build_sched();

// ---------------- static_for ----------------
template<class F, unsigned... I>
__device__ __forceinline__ void static_for_impl(F&& f, std::integer_sequence<unsigned, I...>) {
    (f(std::integral_constant<unsigned, I>{}), ...);
}
template<unsigned N, class F>
__device__ __forceinline__ void static_for(F&& f) {
    static_for_impl(static_cast<F&&>(f), std::make_integer_sequence<unsigned, N>{});
}

// ---------------- packed complex mul/mac ----------------
// cmul: y = k' * x  (complex), k' = (±k.lo, ±k.hi) per NEGLO/NEGHI.
template<int NEGLO, int NEGHI>
__device__ __forceinline__ v2f cmul(v2f k, v2f x) {
    v2f y;
    if constexpr (!NEGLO)
        asm("v_pk_mul_f32 %0, %1, %2 op_sel:[0,0] op_sel_hi:[0,1]"
            : "=&v"(y) : "v"(k), "v"(x));
    else
        asm("v_pk_mul_f32 %0, %1, %2 op_sel:[0,0] op_sel_hi:[0,1] neg_lo:[1,0] neg_hi:[1,0]"
            : "=&v"(y) : "v"(k), "v"(x));
    if constexpr (!NEGHI)
        asm("v_pk_fma_f32 %0, %1, %2, %0 op_sel:[1,1,0] op_sel_hi:[1,0,1] neg_lo:[0,1,0]"
            : "+v"(y) : "v"(k), "v"(x));
    else
        asm("v_pk_fma_f32 %0, %1, %2, %0 op_sel:[1,1,0] op_sel_hi:[1,0,1] neg_lo:[1,1,0] neg_hi:[1,0,0]"
            : "+v"(y) : "v"(k), "v"(x));
    return y;
}
// cmac: y += k' * x
template<int NEGLO, int NEGHI>
__device__ __forceinline__ void cmac(v2f& y, v2f k, v2f x) {
    if constexpr (!NEGLO)
        asm("v_pk_fma_f32 %0, %1, %2, %0 op_sel:[0,0,0] op_sel_hi:[0,1,1]"
            : "+v"(y) : "v"(k), "v"(x));
    else
        asm("v_pk_fma_f32 %0, %1, %2, %0 op_sel:[0,0,0] op_sel_hi:[0,1,1] neg_lo:[1,0,0] neg_hi:[1,0,0]"
            : "+v"(y) : "v"(k), "v"(x));
    if constexpr (!NEGHI)
        asm("v_pk_fma_f32 %0, %1, %2, %0 op_sel:[1,1,0] op_sel_hi:[1,0,1] neg_lo:[0,1,0]"
            : "+v"(y) : "v"(k), "v"(x));
    else
        asm("v_pk_fma_f32 %0, %1, %2, %0 op_sel:[1,1,0] op_sel_hi:[1,0,1] neg_lo:[1,1,0] neg_hi:[1,0,0]"
            : "+v"(y) : "v"(k), "v"(x));
}
// real-input variants: rr = (r, r) pair; default half-selection, signs via neg lists.
// rmul: y = (±k.lo*r, ±k.hi*r)
template<int NEGLO, int NEGHI>
__device__ __forceinline__ v2f rmul(v2f k, v2f rr) {
    v2f y;
    if constexpr (!NEGLO && !NEGHI)
        asm("v_pk_mul_f32 %0, %1, %2"
            : "=v"(y) : "v"(k), "v"(rr));
    else if constexpr (NEGLO && !NEGHI)
        asm("v_pk_mul_f32 %0, %1, %2 neg_lo:[1,0]"
            : "=v"(y) : "v"(k), "v"(rr));
    else if constexpr (!NEGLO && NEGHI)
        asm("v_pk_mul_f32 %0, %1, %2 neg_hi:[1,0]"
            : "=v"(y) : "v"(k), "v"(rr));
    else
        asm("v_pk_mul_f32 %0, %1, %2 neg_lo:[1,0] neg_hi:[1,0]"
            : "=v"(y) : "v"(k), "v"(rr));
    return y;
}
// rmac: y += (±k.lo*r, ±k.hi*r)
template<int NEGLO, int NEGHI>
__device__ __forceinline__ void rmac(v2f& y, v2f k, v2f rr) {
    if constexpr (!NEGLO && !NEGHI)
        asm("v_pk_fma_f32 %0, %1, %2, %0"
            : "+v"(y) : "v"(k), "v"(rr));
    else if constexpr (NEGLO && !NEGHI)
        asm("v_pk_fma_f32 %0, %1, %2, %0 neg_lo:[1,0,0]"
            : "+v"(y) : "v"(k), "v"(rr));
    else if constexpr (!NEGLO && NEGHI)
        asm("v_pk_fma_f32 %0, %1, %2, %0 neg_hi:[1,0,0]"
            : "+v"(y) : "v"(k), "v"(rr));
    else
        asm("v_pk_fma_f32 %0, %1, %2, %0 neg_lo:[1,0,0] neg_hi:[1,0,0]"
            : "+v"(y) : "v"(k), "v"(rr));
}

// ---------------- one phase: 16 amps/thread (NCOS cosets of 2^K) ----------------
template<int PIDX, bool FIRST>
__device__ __forceinline__ void apply_phase(char* psiB, const float4* __restrict__ umat,
                                            unsigned tid, const float* __restrict__ gsrc)
{
    constexpr int K    = SC.ph[PIDX].K;
    constexpr int NLOC = 1 << K;
    constexpr int NCOS = 16 / NLOC;   // cosets per thread; DIM/(16*TPB) == 1
    __syncthreads();

    unsigned repv[NCOS], sb[NCOS];
    static_for<NCOS>([&](auto Cc) {
        constexpr unsigned c = decltype(Cc)::value;
        const unsigned idx = tid + c * TPB;
        unsigned rep = 0;
#pragma unroll
        for (int b = 0; b < 14 - K; ++b)
            rep |= ((idx >> b) & 1u) << SC.ph[PIDX].pos[b];
        repv[c] = rep;
        sb[c] = (rep ^ foldf(rep)) << 3;
    });

    v2f x[16];
    v2f rr[16];   // broadcast real input pairs; used only when FIRST, else DCE'd
    if constexpr (FIRST) {
        static_for<16>([&](auto Sc) {
            constexpr unsigned s = decltype(Sc)::value;
            constexpr unsigned m = SC.ph[PIDX].sx[s];
            float v = gsrc[repv[0] ^ m];
            rr[s] = (v2f){ v, v };
        });
    } else {
        static_for<NCOS>([&](auto Cc) {
            constexpr unsigned c = decltype(Cc)::value;
            static_for<NLOC>([&](auto Sc) {
                constexpr unsigned s   = decltype(Sc)::value;
                constexpr unsigned off = sigma(SC.ph[PIDX].sx[s]) << 3;
                x[c * NLOC + s] = *(const v2f*)(psiB + (sb[c] ^ off));
            });
        });
    }

    static_for<K>([&](auto Qc) {
        constexpr unsigned q  = decltype(Qc)::value;
        constexpr unsigned vm = SC.ph[PIDX].vm[q];
        constexpr unsigned cp = SC.ph[PIDX].cpar[q];
        const float4 u = umat[SC.ph[PIDX].gbase + q];
        static_for<NCOS>([&](auto Cc) {
            constexpr unsigned c = decltype(Cc)::value;
            const unsigned sm = ((unsigned)__popc(repv[c] & vm)) << 31;  // coset parity sign
            v2f A, B;  // A = (ar, ai^s), B = (br^s, bi)
            A.x = u.x; A.y = __uint_as_float(__float_as_uint(u.y) ^ sm);
            B.x = __uint_as_float(__float_as_uint(u.z) ^ sm); B.y = u.w;
            static_for<NLOC / 2>([&](auto Pc) {
                constexpr unsigned p    = decltype(Pc)::value;
                constexpr unsigned lowm = (1u << q) - 1u;
                constexpr unsigned b0   = ((p & ~lowm) << 1) | (p & lowm);
                constexpr unsigned s0   = b0 + c * NLOC;
                constexpr unsigned s1   = s0 | (1u << q);
                constexpr bool     rc   = (cp >> p) & 1u;
                if constexpr (FIRST && q == 0) {
                    const v2f r0 = rr[s0], r1 = rr[s1];
                    if constexpr (!rc) {
                        v2f y0 = rmul<0, 0>(A, r0); rmac<0, 0>(y0, B, r1);
                        v2f y1 = rmul<1, 0>(B, r0); rmac<0, 1>(y1, A, r1);
                        x[s0] = y0; x[s1] = y1;
                    } else {
                        v2f y0 = rmul<0, 1>(A, r0); rmac<1, 0>(y0, B, r1);
                        v2f y1 = rmul<0, 0>(B, r0); rmac<0, 0>(y1, A, r1);
                        x[s0] = y0; x[s1] = y1;
                    }
                } else {
                    const v2f x0 = x[s0], x1 = x[s1];
                    if constexpr (!rc) {
                        v2f y0 = cmul<0, 0>(A, x0); cmac<0, 0>(y0, B, x1);
                        v2f y1 = cmul<1, 0>(B, x0); cmac<0, 1>(y1, A, x1);
                        x[s0] = y0; x[s1] = y1;
                    } else {
                        v2f y0 = cmul<0, 1>(A, x0); cmac<1, 0>(y0, B, x1);
                        v2f y1 = cmul<0, 0>(B, x0); cmac<0, 0>(y1, A, x1);
                        x[s0] = y0; x[s1] = y1;
                    }
                }
            });
        });
    });

    static_for<NCOS>([&](auto Cc) {
        constexpr unsigned c = decltype(Cc)::value;
        static_for<NLOC>([&](auto Sc) {
            constexpr unsigned s   = decltype(Sc)::value;
            constexpr unsigned off = sigma(SC.ph[PIDX].sx[s]) << 3;
            *(v2f*)(psiB + (sb[c] ^ off)) = x[c * NLOC + s];
        });
    });
}

__global__ __launch_bounds__(TPB) void qsim_kernel(
    const float* __restrict__ state,
    const float* __restrict__ params,
    const float* __restrict__ head_w,
    const float* __restrict__ head_b,
    float* __restrict__ out)
{
    __shared__ v2f    psi[DIM];          // 128 KB
    __shared__ float4 umat[NGATES];
    __shared__ float  red[TPB / 64];
    char* psiB = (char*)psi;

    const unsigned tid = threadIdx.x;

    // Fused U = RY(t2)*RX(t1) = [[a,b],[-conj(b),conj(a)]]; a=(c1c2,s1s2), b=(-s2c1,-c2s1)
    if (tid < NGATES) {
        float t1 = 0.5f * params[2 * tid + 0];
        float t2 = 0.5f * params[2 * tid + 1];
        float s1, c1, s2, c2;
        sincosf(t1, &s1, &c1);
        sincosf(t2, &s2, &c2);
        umat[tid] = make_float4(c1 * c2, s1 * s2, -s2 * c1, -c2 * s1);
    }

    // Phase 0 reads the (real) state directly from global; staging sweep eliminated.
    const float* gsrc = state + (size_t)blockIdx.x * DIM;
    apply_phase<0, true>(psiB, umat, tid, gsrc);
    static_for<NPH - 1>([&](auto Pi) {
        apply_phase<(int)decltype(Pi)::value + 1, false>(psiB, umat, tid, gsrc);
    });

    __syncthreads();

    // ---- Measurement: out = sum_i |psi_i|^2 * c(i) + head_b
    // c over the 4 high index bits via 16-point Walsh-Hadamard of compile-time groups;
    // low-10-bit signs folded into e[w].
    float e[NW];
    static_for<NW>([&](auto Wc) {
        constexpr int      w    = decltype(Wc)::value;
        constexpr unsigned zlow = SC.zm[w] & (TPB - 1);
        float hw = head_w[w];
        e[w] = (__popc(tid & zlow) & 1) ? -hw : hw;
    });
    float c[16];
    static_for<16>([&](auto Mc) { c[decltype(Mc)::value] = 0.f; });
    static_for<NW>([&](auto Wc) {
        constexpr int      w = decltype(Wc)::value;
        constexpr unsigned m = SC.zm[w] >> 10;
        c[m] += e[w];
    });
    static_for<4>([&](auto Bc) {
        constexpr unsigned B = 1u << decltype(Bc)::value;
        static_for<16>([&](auto Kc) {
            constexpr unsigned k = decltype(Kc)::value;
            if constexpr (!(k & B)) {
                float a = c[k], b = c[k | B];
                c[k] = a + b; c[k | B] = a - b;
            }
        });
    });

    const unsigned baseB = (tid ^ foldf(tid)) << 3;
    float acc = 0.f;
    static_for<16>([&](auto Kc) {
        constexpr int k = decltype(Kc)::value;
        v2f a = *(const v2f*)(psiB + baseB + k * (TPB * 8));
        acc += (a.x * a.x + a.y * a.y) * c[k];
    });

#pragma unroll
    for (int off = 32; off > 0; off >>= 1)
        acc += __shfl_down(acc, off, 64);
    const unsigned lane = tid & 63, wv = tid >> 6;
    if (lane == 0) red[wv] = acc;
    __syncthreads();
    if (tid == 0) {
        float tot = 0.f;
#pragma unroll
        for (int i = 0; i < TPB / 64; ++i) tot += red[i];
        out[blockIdx.x] = tot + head_b[0];
    }
}

extern "C" void kernel_launch(void* const* d_in, const int* in_sizes, int n_in,
                              void* d_out, int out_size, void* d_ws, size_t ws_size,
                              hipStream_t stream) {
    const float* state  = (const float*)d_in[0];   // (1024, 16384) f32
    const float* params = (const float*)d_in[1];   // (3, 14, 2) f32
    const float* head_w = (const float*)d_in[2];   // (1, 14) f32
    const float* head_b = (const float*)d_in[3];   // (1,) f32
    float* out = (float*)d_out;                    // (1024,) f32

    qsim_kernel<<<out_size, TPB, 0, stream>>>(state, params, head_w, head_b, out);
}